// Round 4
// baseline (692.385 us; speedup 1.0000x reference)
//
#include <hip/hip_runtime.h>
#include <hip/hip_bf16.h>
#include <math.h>

#define B_  2
#define T_  2048
#define D_  512
#define H_  8
#define HD_ 64
#define FFN_ 2048
#define VOCAB_ 256
#define BT_ (B_*T_)
#define QKVS_ 1536        // fused qkv row stride
#define NC_ 32            // chunks per (b,h), chunk size 64
#define CENT_ 4160        // floats per chunk state: 64*64 S + 64 z

typedef __attribute__((ext_vector_type(8))) short short8;
typedef __attribute__((ext_vector_type(4))) float float4v;
typedef __hip_bfloat16 bf16;

// ---------------------------------------------------------------------------
// Embedding + sinusoidal positional concat; writes fp32 x and bf16 mirror xb
// ---------------------------------------------------------------------------
__global__ __launch_bounds__(512) void embed_pos_kernel(
    const int* __restrict__ tokens, const float* __restrict__ emb,
    float* __restrict__ x, bf16* __restrict__ xb)
{
  int bt = blockIdx.x;          // b*T + t
  int t  = bt & (T_ - 1);
  int j  = threadIdx.x;
  float val;
  if (j < 256) {
    int tok = tokens[bt];
    val = emb[tok * 256 + j];
  } else {
    int jj = (j - 256) & 127;
    float f = expf(-(float)(2 * jj) * (9.210340371976184f / 256.0f));
    float arg = (float)t * f;
    val = (j < 384) ? sinf(arg) : cosf(arg);
  }
  size_t off = (size_t)bt * D_ + j;
  x[off]  = val;
  xb[off] = __float2bfloat16(val);
}

// ---------------------------------------------------------------------------
// Transpose-cast: W fp32 [K,N] (layer via blockIdx.z) -> Wt bf16 rows
// [dstOff + n][k], dest layer stride dstLayerStride elements.
// ---------------------------------------------------------------------------
__global__ __launch_bounds__(256) void transpose_cast_kernel(
    const float* __restrict__ W, bf16* __restrict__ Wt, int K, int N,
    int dstOff, long dstLayerStride)
{
  __shared__ float t[32][33];
  int n0 = blockIdx.x * 32, k0 = blockIdx.y * 32;
  const float* Wl = W + (size_t)blockIdx.z * K * N;
  bf16* Wtl = Wt + (size_t)blockIdx.z * dstLayerStride;
  int tx = threadIdx.x & 31, ty = threadIdx.x >> 5;  // ty 0..7
#pragma unroll
  for (int r = 0; r < 4; ++r)
    t[ty + 8 * r][tx] = Wl[(size_t)(k0 + ty + 8 * r) * N + n0 + tx];
  __syncthreads();
#pragma unroll
  for (int r = 0; r < 4; ++r)
    Wtl[(size_t)(dstOff + n0 + ty + 8 * r) * K + k0 + tx] =
        __float2bfloat16(t[tx][ty + 8 * r]);
}

// ---------------------------------------------------------------------------
// Concat qkv biases: bqkv[l][1536] = [bq[l] | bk[l] | bv[l]]
// ---------------------------------------------------------------------------
__global__ __launch_bounds__(256) void bias_cat_kernel(
    const float* __restrict__ bq, const float* __restrict__ bk,
    const float* __restrict__ bv, float* __restrict__ bqkv)
{
  int i = blockIdx.x * 256 + threadIdx.x;      // 0..3071
  int l = i / QKVS_, j = i % QKVS_;
  float v = (j < 512) ? bq[l * 512 + j]
          : (j < 1024) ? bk[l * 512 + j - 512]
                       : bv[l * 512 + j - 1024];
  bqkv[i] = v;
}

// ---------------------------------------------------------------------------
// bf16 MFMA GEMM: C[M,N] = act(A[M,K] @ Bt[N,K]^T + bias[N])
// BM x BN tile, BK=32, 256 threads = 4 waves arranged WR x WC; each wave
// computes (BM/WR) x (BN/WC) via 16x16x32 frags.
// mode 0: store fp32. mode 1: gelu, store bf16.
// ---------------------------------------------------------------------------
template<int BM, int BN, int WR, int WC>
__global__ __launch_bounds__(256) void gemm_mfma(
    const bf16* __restrict__ A, const bf16* __restrict__ Bt,
    const float* __restrict__ bias, void* __restrict__ Cout,
    int M, int N, int K, int mode)
{
  constexpr int MI = BM / WR / 16;
  constexpr int NI = BN / WC / 16;
  constexpr int PASSES = (BM + BN) / 64;
  __shared__ short Sl[(BM + BN) * 32];   // A rows then B rows, k contiguous
  short* Al = Sl;
  short* Bl = Sl + BM * 32;
  int tid = threadIdx.x;
  int lane = tid & 63, w = tid >> 6;
  int row0 = blockIdx.y * BM, col0 = blockIdx.x * BN;
  int wr = w / WC, wc = w % WC;
  int wm = wr * (BM / WR), wn = wc * (BN / WC);
  int quad = lane >> 4, l16 = lane & 15;
  float4v acc[MI][NI] = {};

  // staging: thread owns 16B at combined row (p*64 + tid>>2), k-offset (tid&3)*8
  int sr = tid >> 2;
  int sk = (tid & 3) * 8;
  const short* gp[PASSES];
#pragma unroll
  for (int p = 0; p < PASSES; ++p) {
    int cr = p * 64 + sr;
    gp[p] = (cr < BM) ? (const short*)A + (size_t)(row0 + cr) * K + sk
                      : (const short*)Bt + (size_t)(col0 + (cr - BM)) * K + sk;
  }
  uint4 st[PASSES];
#pragma unroll
  for (int p = 0; p < PASSES; ++p) st[p] = *(const uint4*)gp[p];

  const int kr = K >> 5;
  for (int kt = 0; kt < kr; ++kt) {
    __syncthreads();               // previous compute done
#pragma unroll
    for (int p = 0; p < PASSES; ++p)
      *(uint4*)&Sl[(p * 64 + sr) * 32 + sk] = st[p];
    __syncthreads();
    if (kt + 1 < kr) {             // prefetch next tile (overlaps compute)
#pragma unroll
      for (int p = 0; p < PASSES; ++p)
        st[p] = *(const uint4*)(gp[p] + (kt + 1) * 32);
    }
    short8 af[MI], bfr[NI];
#pragma unroll
    for (int mi = 0; mi < MI; ++mi)
      af[mi] = *(const short8*)&Al[(wm + mi * 16 + l16) * 32 + quad * 8];
#pragma unroll
    for (int ni = 0; ni < NI; ++ni)
      bfr[ni] = *(const short8*)&Bl[(wn + ni * 16 + l16) * 32 + quad * 8];
#pragma unroll
    for (int mi = 0; mi < MI; ++mi)
#pragma unroll
      for (int ni = 0; ni < NI; ++ni)
        acc[mi][ni] = __builtin_amdgcn_mfma_f32_16x16x32_bf16(
            af[mi], bfr[ni], acc[mi][ni], 0, 0, 0);
  }

  // epilogue: C[i][j], i = row0+wm+mi*16+quad*4+r, j = col0+wn+ni*16+l16
#pragma unroll
  for (int mi = 0; mi < MI; ++mi) {
#pragma unroll
    for (int ni = 0; ni < NI; ++ni) {
      int j = col0 + wn + ni * 16 + l16;
      float bj = bias[j];
#pragma unroll
      for (int r = 0; r < 4; ++r) {
        int i = row0 + wm + mi * 16 + quad * 4 + r;
        float v = acc[mi][ni][r] + bj;
        if (mode == 1) {
          v = 0.5f * v * (1.0f + erff(v * 0.7071067811865475f));
          ((bf16*)Cout)[(size_t)i * N + j] = __float2bfloat16(v);
        } else {
          ((float*)Cout)[(size_t)i * N + j] = v;
        }
      }
    }
  }
}

// ---------------------------------------------------------------------------
// FAVOR+ feature map, in place on fused qkv buffer (q and k halves).
// One wave per (bth, side) unit; 4 waves per block.
// ---------------------------------------------------------------------------
__global__ __launch_bounds__(256) void favor_kernel(
    float* __restrict__ qkv, const float* __restrict__ rfs)
{
  int u = blockIdx.x * 4 + (threadIdx.x >> 6);  // 0 .. 2*BT*H-1
  int m = threadIdx.x & 63;
  int bth = u >> 1;
  int side = u & 1;                 // 0: q (col 0), 1: k (col 512)
  int h = bth & 7;
  int bt = bth >> 3;
  __shared__ float xps[4][64];
  float* xp = xps[threadIdx.x >> 6];
  size_t off = (size_t)bt * QKVS_ + side * 512 + h * 64;
  xp[m] = qkv[off + m] * 0.35355339059327373f;   // 64^-0.25
  __syncthreads();
  const float* R = rfs + h * 64 * 64;
  float sq = 0.f, dot = 0.f;
#pragma unroll 8
  for (int dd = 0; dd < 64; ++dd) {
    float xv = xp[dd];
    sq  += xv * xv;
    dot += xv * R[dd * 64 + m];
  }
  qkv[off + m] = __expf(dot - 0.5f * sq);
}

// ---------------------------------------------------------------------------
// Pass 1: per-chunk sums (chunks 0..30 per bh), from fused qkv buffer
// ---------------------------------------------------------------------------
__global__ __launch_bounds__(256) void chunk_sum_kernel(
    const float* __restrict__ qkv, float* __restrict__ buf)
{
  int bh = blockIdx.x / 31;
  int c  = blockIdx.x % 31;
  int b = bh >> 3, h = bh & 7;
  __shared__ float Ks[64][68], Vs[64][68];
  int tid = threadIdx.x;
  int d = tid & 63, g = tid >> 6;
  for (int t4 = 0; t4 < 64; t4 += 4) {
    int t = t4 + g;
    size_t off = ((size_t)(b * T_ + c * 64 + t) * QKVS_) + h * 64 + d;
    Ks[t][d] = qkv[off + 512];
    Vs[t][d] = qkv[off + 1024];
  }
  __syncthreads();
  float acc[16];
#pragma unroll
  for (int i = 0; i < 16; ++i) acc[i] = 0.f;
  for (int t = 0; t < 64; ++t) {
    float vv = Vs[t][d];
#pragma unroll
    for (int i = 0; i < 16; ++i) acc[i] += Ks[t][g * 16 + i] * vv;
  }
  size_t bo = (size_t)(bh * 31 + c) * CENT_;
#pragma unroll
  for (int i = 0; i < 16; ++i) buf[bo + (size_t)(g * 16 + i) * 64 + d] = acc[i];
  if (tid < 64) {
    float zz = 0.f;
    for (int t = 0; t < 64; ++t) zz += Ks[t][tid];
    buf[bo + 4096 + tid] = zz;
  }
}

// ---------------------------------------------------------------------------
// Pass 2: inclusive scan over 31 chunk states per (b,h)
// ---------------------------------------------------------------------------
__global__ __launch_bounds__(256) void chunk_prefix_kernel(float* __restrict__ buf)
{
  int bh = blockIdx.x / 17;
  int grp = blockIdx.x % 17;
  int e = grp * 256 + threadIdx.x;
  if (e >= CENT_) return;
  size_t base = (size_t)bh * 31 * CENT_ + e;
  float run = 0.f;
  for (int c = 0; c < 31; ++c) {
    run += buf[base + (size_t)c * CENT_];
    buf[base + (size_t)c * CENT_] = run;
  }
}

// ---------------------------------------------------------------------------
// Pass 3: per-chunk attention (pad 65: lane-indexed rows -> conflict-free)
// ---------------------------------------------------------------------------
__global__ __launch_bounds__(256) void chunk_attn_kernel(
    const float* __restrict__ qkv, const float* __restrict__ buf,
    float* __restrict__ out)
{
  int bh = blockIdx.x >> 5;
  int c  = blockIdx.x & 31;
  int b = bh >> 3, h = bh & 7;
  __shared__ float Qs[64][65], Ks[64][65], Vs[64][65];  // Ks reused for A
  __shared__ float den[64];
  int tid = threadIdx.x;
  int d = tid & 63, g = tid >> 6;
  for (int t4 = 0; t4 < 64; t4 += 4) {
    int t = t4 + g;
    size_t off = ((size_t)(b * T_ + c * 64 + t) * QKVS_) + h * 64 + d;
    Qs[t][d] = qkv[off];
    Ks[t][d] = qkv[off + 512];
    Vs[t][d] = qkv[off + 1024];
  }
  __syncthreads();
  float a[16];
  {
    int i = d;
#pragma unroll
    for (int jj = 0; jj < 16; ++jj) a[jj] = 0.f;
    for (int m = 0; m < 64; ++m) {
      float qv = Qs[i][m];
#pragma unroll
      for (int jj = 0; jj < 16; ++jj) a[jj] += qv * Ks[g * 16 + jj][m];
    }
  }
  __syncthreads();
  {
    int i = d;
#pragma unroll
    for (int jj = 0; jj < 16; ++jj) {
      int j = g * 16 + jj;
      Ks[i][j] = (j <= i) ? a[jj] : 0.f;
    }
  }
  __syncthreads();
  const float* S0 = buf + (size_t)(bh * 31 + (c - 1)) * CENT_;  // valid if c>0
  if (tid < 64) {
    int i = tid;
    float dn = 0.f;
    for (int j = 0; j < 64; ++j) dn += Ks[i][j];
    if (c > 0) {
      const float* z0 = S0 + 4096;
      for (int m = 0; m < 64; ++m) dn += Qs[i][m] * z0[m];
    }
    den[i] = dn;
  }
  float acc[16];
#pragma unroll
  for (int ii = 0; ii < 16; ++ii) acc[ii] = 0.f;
  for (int j = 0; j < 64; ++j) {
    float vv = Vs[j][d];
#pragma unroll
    for (int ii = 0; ii < 16; ++ii) acc[ii] += Ks[g * 16 + ii][j] * vv;
  }
  if (c > 0) {
    for (int m = 0; m < 64; ++m) {
      float s0 = S0[(size_t)m * 64 + d];
#pragma unroll
      for (int ii = 0; ii < 16; ++ii) acc[ii] += Qs[g * 16 + ii][m] * s0;
    }
  }
  __syncthreads();
#pragma unroll
  for (int ii = 0; ii < 16; ++ii) {
    int i = g * 16 + ii;
    size_t off = ((size_t)(b * T_ + c * 64 + i) * D_) + h * 64 + d;
    out[off] = acc[ii] / (den[i] + 1e-16f);
  }
}

// ---------------------------------------------------------------------------
// x[row,:] += LayerNorm(a[row,:]) * g + b ; also writes bf16 mirror xb
// ---------------------------------------------------------------------------
__global__ __launch_bounds__(256) void ln_add_kernel(
    float* __restrict__ x, bf16* __restrict__ xb, const float* __restrict__ a,
    const float* __restrict__ g, const float* __restrict__ bta)
{
  int row = blockIdx.x;
  int tid = threadIdx.x;
  const float* ar = a + (size_t)row * D_;
  float v0 = ar[tid], v1 = ar[tid + 256];
  __shared__ float red[4];
  float w = v0 + v1;
  for (int o = 32; o > 0; o >>= 1) w += __shfl_down(w, o, 64);
  if ((tid & 63) == 0) red[tid >> 6] = w;
  __syncthreads();
  float mu = (red[0] + red[1] + red[2] + red[3]) * (1.f / 512.f);
  float d0 = v0 - mu, d1 = v1 - mu;
  __syncthreads();
  w = d0 * d0 + d1 * d1;
  for (int o = 32; o > 0; o >>= 1) w += __shfl_down(w, o, 64);
  if ((tid & 63) == 0) red[tid >> 6] = w;
  __syncthreads();
  float var = (red[0] + red[1] + red[2] + red[3]) * (1.f / 512.f);
  float rs = rsqrtf(var + 1e-5f);
  size_t xoff = (size_t)row * D_;
  float n0 = x[xoff + tid]       + d0 * rs * g[tid]       + bta[tid];
  float n1 = x[xoff + tid + 256] + d1 * rs * g[tid + 256] + bta[tid + 256];
  x[xoff + tid]        = n0;
  x[xoff + tid + 256]  = n1;
  xb[xoff + tid]       = __float2bfloat16(n0);
  xb[xoff + tid + 256] = __float2bfloat16(n1);
}

// ---------------------------------------------------------------------------
extern "C" void kernel_launch(void* const* d_in, const int* in_sizes, int n_in,
                              void* d_out, int out_size, void* d_ws, size_t ws_size,
                              hipStream_t stream) {
  const int*   tokens = (const int*)  d_in[0];
  const float* emb    = (const float*)d_in[1];
  const float* Wq     = (const float*)d_in[2];
  const float* bq     = (const float*)d_in[3];
  const float* Wk     = (const float*)d_in[4];
  const float* bk     = (const float*)d_in[5];
  const float* Wv     = (const float*)d_in[6];
  const float* bv     = (const float*)d_in[7];
  const float* rfs    = (const float*)d_in[8];
  const float* ln1g   = (const float*)d_in[9];
  const float* ln1b   = (const float*)d_in[10];
  const float* ln2g   = (const float*)d_in[11];
  const float* ln2b   = (const float*)d_in[12];
  const float* WU     = (const float*)d_in[13];
  const float* bU     = (const float*)d_in[14];
  const float* WV     = (const float*)d_in[15];
  const float* bV     = (const float*)d_in[16];
  const float* Wout   = (const float*)d_in[17];
  const float* bout   = (const float*)d_in[18];
  float* out = (float*)d_out;

  const size_t R = (size_t)BT_ * D_;          // 2,097,152 floats (8 MB)
  float* ws  = (float*)d_ws;
  float* x   = ws;                            // R
  float* ab  = ws + R;                        // R
  float* qkv = ws + 2 * R;                    // 3R  [BT][1536]
  float* sb  = ws + 5 * R;                    // chunk states (uses <R)
  bf16*  xb  = (bf16*)(ws + 6 * R);           // R elems
  bf16*  hb  = (bf16*)(ws + 6 * R + R / 2);   // BT*FFN elems (2R floats)
  bf16*  WqkvT = (bf16*)(ws + 6 * R + R / 2 + 2 * R);   // [L][1536][512]
  bf16*  WUT   = WqkvT + (size_t)2 * QKVS_ * D_;        // [L][FFN][D]
  bf16*  WVT   = WUT   + (size_t)2 * D_ * FFN_;         // [L][D][FFN]
  bf16*  WoutT = WVT   + (size_t)2 * FFN_ * D_;         // [VOCAB][D]
  float* bqkv  = (float*)(WoutT + (size_t)VOCAB_ * D_); // [L][1536]

  // ---- weight prep ----
  transpose_cast_kernel<<<dim3(16, 16, 2), 256, 0, stream>>>(Wq, WqkvT, D_, D_, 0,    (long)QKVS_ * D_);
  transpose_cast_kernel<<<dim3(16, 16, 2), 256, 0, stream>>>(Wk, WqkvT, D_, D_, 512,  (long)QKVS_ * D_);
  transpose_cast_kernel<<<dim3(16, 16, 2), 256, 0, stream>>>(Wv, WqkvT, D_, D_, 1024, (long)QKVS_ * D_);
  transpose_cast_kernel<<<dim3(64, 16, 2), 256, 0, stream>>>(WU, WUT, D_, FFN_, 0, (long)FFN_ * D_);
  transpose_cast_kernel<<<dim3(16, 64, 2), 256, 0, stream>>>(WV, WVT, FFN_, D_, 0, (long)D_ * FFN_);
  transpose_cast_kernel<<<dim3(8, 16, 1),  256, 0, stream>>>(Wout, WoutT, D_, VOCAB_, 0, 0);
  bias_cat_kernel<<<12, 256, 0, stream>>>(bq, bk, bv, bqkv);

  embed_pos_kernel<<<BT_, 512, 0, stream>>>(tokens, emb, x, xb);

  for (int l = 0; l < 2; ++l) {
    // fused QKV: [BT,512] x [512,1536]
    gemm_mfma<128,128,2,2><<<dim3(QKVS_/128, BT_/128), 256, 0, stream>>>(
        xb, WqkvT + (size_t)l * QKVS_ * D_, bqkv + l * QKVS_, qkv, BT_, QKVS_, D_, 0);

    const float* rfl = rfs + (size_t)l * H_ * 64 * 64;
    favor_kernel<<<2 * BT_ * H_ / 4, 256, 0, stream>>>(qkv, rfl);

    chunk_sum_kernel<<<16 * 31, 256, 0, stream>>>(qkv, sb);
    chunk_prefix_kernel<<<16 * 17, 256, 0, stream>>>(sb);
    chunk_attn_kernel<<<16 * NC_, 256, 0, stream>>>(qkv, sb, ab);

    ln_add_kernel<<<BT_, 256, 0, stream>>>(x, xb, ab, ln1g + l*D_, ln1b + l*D_);

    gemm_mfma<128,128,2,2><<<dim3(FFN_/128, BT_/128), 256, 0, stream>>>(
        xb, WUT + (size_t)l * D_ * FFN_, bU + l * FFN_, hb, BT_, FFN_, D_, 1);
    gemm_mfma<64,128,1,4><<<dim3(D_/128, BT_/64), 256, 0, stream>>>(
        hb, WVT + (size_t)l * FFN_ * D_, bV + l * D_, ab, BT_, D_, FFN_, 0);

    ln_add_kernel<<<BT_, 256, 0, stream>>>(x, xb, ab, ln2g + l*D_, ln2b + l*D_);
  }

  gemm_mfma<64,64,1,4><<<dim3(VOCAB_/64, BT_/64), 256, 0, stream>>>(
      xb, WoutT, bout, out, BT_, VOCAB_, D_, 0);
}